// Round 1
// baseline (5671.682 us; speedup 1.0000x reference)
//
#include <hip/hip_runtime.h>

#define E_  256
#define H_  512
#define B_  16
#define TE_ 64
#define TD_ 32
#define V_  90000
#define G4_ 2048
#define AHP 1028
#define NWG 32

typedef __attribute__((ext_vector_type(8))) short short8;
typedef __attribute__((ext_vector_type(4))) float f32x4;

__device__ __forceinline__ float sigm(float x) { return 1.f / (1.f + __expf(-x)); }
__device__ __forceinline__ float tanh_(float x) {
  float e = __expf(-2.f * fabsf(x));
  float r = (1.f - e) / (1.f + e);
  return x >= 0.f ? r : -r;
}
__device__ __forceinline__ unsigned short f2bf(float v) {
  union { float f; unsigned u; } c; c.f = v;
  unsigned r = c.u + 0x7FFFu + ((c.u >> 16) & 1u);
  return (unsigned short)(r >> 16);
}

// ---------------- transpose (tiled 32x32) of the 5 recurrent weight blocks ----------------
__global__ __launch_bounds__(256) void k_tr(
    const float* __restrict__ W_enc, const float* __restrict__ W_dec,
    const float* __restrict__ W_query, const float* __restrict__ W_mem,
    const float* __restrict__ W_attn,
    float* __restrict__ UeT, float* __restrict__ UdT, float* __restrict__ WqT,
    float* __restrict__ WmT, float* __restrict__ WaT)
{
  int bid = blockIdx.x;
  const float* src; float* dst; int R, C, lb;
  if (bid < 1024)      { src = W_enc + 256 * G4_; dst = UeT; R = 512;  C = G4_; lb = bid; }
  else if (bid < 3072) { src = W_dec + 256 * G4_; dst = UdT; R = 1024; C = G4_; lb = bid - 1024; }
  else if (bid < 3328) { src = W_query;           dst = WqT; R = 512;  C = 512; lb = bid - 3072; }
  else if (bid < 3584) { src = W_mem;             dst = WmT; R = 512;  C = 512; lb = bid - 3328; }
  else                 { src = W_attn;            dst = WaT; R = 1024; C = 512; lb = bid - 3584; }
  int ctiles = C >> 5;
  int br = lb / ctiles, bc = lb % ctiles;
  __shared__ float tile[32][33];
  int tx = threadIdx.x & 31, ty = threadIdx.x >> 5;
  #pragma unroll
  for (int j = 0; j < 4; ++j)
    tile[ty + j * 8][tx] = src[(size_t)(br * 32 + ty + j * 8) * C + bc * 32 + tx];
  __syncthreads();
  #pragma unroll
  for (int j = 0; j < 4; ++j)
    dst[(size_t)(bc * 32 + ty + j * 8) * R + br * 32 + tx] = tile[tx][ty + j * 8];
}

// ---------------- x-part of LSTM gates: Xg[tok][2048] = emb[tok]@W[0:256,:] + b ----------------
__global__ __launch_bounds__(256) void k_xg(
    const int* __restrict__ toks, const float* __restrict__ emb,
    const float* __restrict__ W, const float* __restrict__ bias,
    float* __restrict__ Xg)
{
  const int tid = threadIdx.x;
  const int cc = tid & 63;
  const int tg = tid >> 6;
  const int col = blockIdx.x * 64 + cc;
  const int t0 = blockIdx.y * 64 + tg * 16;
  const float* ep[16];
  #pragma unroll
  for (int i = 0; i < 16; ++i) ep[i] = emb + (size_t)toks[t0 + i] * E_;
  float acc[16];
  float bv = bias[col];
  #pragma unroll
  for (int i = 0; i < 16; ++i) acc[i] = bv;
  for (int k4 = 0; k4 < 64; ++k4) {
    float w0 = W[(size_t)(k4 * 4 + 0) * G4_ + col];
    float w1 = W[(size_t)(k4 * 4 + 1) * G4_ + col];
    float w2 = W[(size_t)(k4 * 4 + 2) * G4_ + col];
    float w3 = W[(size_t)(k4 * 4 + 3) * G4_ + col];
    #pragma unroll
    for (int i = 0; i < 16; ++i) {
      float4 e4 = *(const float4*)(ep[i] + k4 * 4);
      acc[i] += e4.x * w0 + e4.y * w1 + e4.z * w2 + e4.w * w3;
    }
  }
  #pragma unroll
  for (int i = 0; i < 16; ++i)
    Xg[(size_t)(t0 + i) * G4_ + col] = acc[i];
}

// ---------------- persistent recurrent kernel: encoder LSTM + keys + attention decoder ----------------
__device__ __forceinline__ void gbar(unsigned* bar, unsigned* nbar) {
  __syncthreads();
  if (threadIdx.x == 0) {
    __threadfence();
    __hip_atomic_fetch_add(bar, 1u, __ATOMIC_RELEASE, __HIP_MEMORY_SCOPE_AGENT);
    unsigned tgt = (*nbar + 1u) * (unsigned)NWG;
    while (__hip_atomic_load(bar, __ATOMIC_ACQUIRE, __HIP_MEMORY_SCOPE_AGENT) < tgt)
      __builtin_amdgcn_s_sleep(2);
  }
  __syncthreads();
  __threadfence();
  ++(*nbar);
}

__global__ __launch_bounds__(512) void k_coop(
    const int* __restrict__ enc_len_g, const float* __restrict__ v_att,
    const float* __restrict__ Xge, const float* __restrict__ Xgd,
    const float* __restrict__ UeT, const float* __restrict__ UdT,
    const float* __restrict__ WqT, const float* __restrict__ WmT,
    const float* __restrict__ WaT,
    float* __restrict__ h_buf, float* __restrict__ attn_buf,
    float* __restrict__ ctx_buf, float* __restrict__ pq_buf,
    float* __restrict__ enc_out, float* __restrict__ keys,
    unsigned short* __restrict__ attn_bf, unsigned* bar)
{
  __shared__ float ah[16 * AHP + 256];   // staging: [attn|h] rows (pitch AHP); reused (pitch 520) for keys
  __shared__ float z_lds[16][4][16];
  __shared__ float c_lds[16][16];
  __shared__ float sc_part[64][9];
  __shared__ float align_l[64];
  __shared__ float pq_l[512];
  __shared__ float v_l[512];
  __shared__ int el[16];

  const int tid = threadIdx.x;
  const int wg = blockIdx.x;
  unsigned nbar = 0;

  if (tid < 16) el[tid] = enc_len_g[tid];
  v_l[tid] = v_att[tid];
  if (tid < 256) c_lds[tid & 15][tid >> 4] = 0.f;

  const int b = tid & 15;
  const int jc = (tid >> 4) & 7;
  const int g = tid >> 7;
  const int gc0 = g * 512 + wg * 16 + jc * 2;

  // ================= encoder =================
  for (int t = 0; t < TE_; ++t) {
    #pragma unroll
    for (int i = 0; i < 4; ++i) {
      int idx4 = tid + i * 512;
      int rb = idx4 >> 7, k4 = idx4 & 127;
      *(float4*)&ah[rb * AHP + 512 + k4 * 4] = *(const float4*)&h_buf[rb * 512 + k4 * 4];
    }
    __syncthreads();
    float acc0 = Xge[(size_t)(b * TE_ + t) * G4_ + gc0];
    float acc1 = Xge[(size_t)(b * TE_ + t) * G4_ + gc0 + 1];
    const float4* u0 = (const float4*)(UeT + (size_t)gc0 * 512);
    const float4* u1 = (const float4*)(UeT + (size_t)(gc0 + 1) * 512);
    const float4* hv = (const float4*)&ah[b * AHP + 512];
    #pragma unroll 8
    for (int k4 = 0; k4 < 128; ++k4) {
      float4 h4 = hv[k4], a4 = u0[k4], c4 = u1[k4];
      acc0 += h4.x * a4.x + h4.y * a4.y + h4.z * a4.z + h4.w * a4.w;
      acc1 += h4.x * c4.x + h4.y * c4.y + h4.z * c4.z + h4.w * c4.w;
    }
    z_lds[b][g][jc * 2] = acc0;
    z_lds[b][g][jc * 2 + 1] = acc1;
    __syncthreads();
    if (tid < 256) {
      int b2 = tid & 15, cc = tid >> 4;
      float zi = z_lds[b2][0][cc], zj = z_lds[b2][1][cc];
      float zf = z_lds[b2][2][cc], zo = z_lds[b2][3][cc];
      float co = c_lds[b2][cc];
      float c2 = co * sigm(zf + 1.f) + sigm(zi) * tanh_(zj);
      float h2 = tanh_(c2) * sigm(zo);
      bool valid = t < el[b2];
      float hp = ah[b2 * AHP + 512 + wg * 16 + cc];
      c_lds[b2][cc] = valid ? c2 : co;
      h_buf[b2 * 512 + wg * 16 + cc] = valid ? h2 : hp;
      enc_out[(size_t)(b2 * TE_ + t) * 512 + wg * 16 + cc] = valid ? h2 : 0.f;
    }
    gbar(bar, &nbar);
  }

  // ================= keys = enc_out @ W_mem =================
  {
    const int r0 = wg * 32;
    #pragma unroll
    for (int i = 0; i < 8; ++i) {
      int idx4 = tid + i * 512;
      int rr = idx4 >> 7, k4 = idx4 & 127;
      *(float4*)&ah[rr * 520 + k4 * 4] = *(const float4*)&enc_out[(size_t)(r0 + rr) * 512 + k4 * 4];
    }
    __syncthreads();
    int rl = tid >> 4, ccc = tid & 15;
    const float4* er = (const float4*)&ah[rl * 520];
    for (int c0 = ccc; c0 < 512; c0 += 16) {
      const float4* wr = (const float4*)(WmT + (size_t)c0 * 512);
      float acc = 0.f;
      #pragma unroll 8
      for (int k4 = 0; k4 < 128; ++k4) {
        float4 e4 = er[k4], w4 = wr[k4];
        acc += e4.x * w4.x + e4.y * w4.y + e4.z * w4.z + e4.w * w4.w;
      }
      keys[(size_t)(r0 + rl) * 512 + c0] = acc;
    }
  }
  gbar(bar, &nbar);

  // ================= decoder =================
  for (int t = 0; t < TD_; ++t) {
    // ---- D1: gates = Xgd + [attn|h] @ U_dec; LSTM pointwise ----
    #pragma unroll
    for (int i = 0; i < 8; ++i) {
      int idx4 = tid + i * 512;
      int rb = idx4 >> 8, k4 = idx4 & 255;
      float4 v;
      if (k4 < 128) v = *(const float4*)&attn_buf[rb * 512 + k4 * 4];
      else          v = *(const float4*)&h_buf[rb * 512 + (k4 - 128) * 4];
      *(float4*)&ah[rb * AHP + k4 * 4] = v;
    }
    __syncthreads();
    float acc0 = Xgd[(size_t)(b * TD_ + t) * G4_ + gc0];
    float acc1 = Xgd[(size_t)(b * TD_ + t) * G4_ + gc0 + 1];
    const float4* u0 = (const float4*)(UdT + (size_t)gc0 * 1024);
    const float4* u1 = (const float4*)(UdT + (size_t)(gc0 + 1) * 1024);
    const float4* av = (const float4*)&ah[b * AHP];
    #pragma unroll 8
    for (int k4 = 0; k4 < 256; ++k4) {
      float4 h4 = av[k4], a4 = u0[k4], c4 = u1[k4];
      acc0 += h4.x * a4.x + h4.y * a4.y + h4.z * a4.z + h4.w * a4.w;
      acc1 += h4.x * c4.x + h4.y * c4.y + h4.z * c4.z + h4.w * c4.w;
    }
    z_lds[b][g][jc * 2] = acc0;
    z_lds[b][g][jc * 2 + 1] = acc1;
    __syncthreads();
    if (tid < 256) {
      int b2 = tid & 15, cc = tid >> 4;
      float zi = z_lds[b2][0][cc], zj = z_lds[b2][1][cc];
      float zf = z_lds[b2][2][cc], zo = z_lds[b2][3][cc];
      float co = c_lds[b2][cc];
      float c2 = co * sigm(zf + 1.f) + sigm(zi) * tanh_(zj);
      float h2 = tanh_(c2) * sigm(zo);
      c_lds[b2][cc] = c2;
      h_buf[b2 * 512 + wg * 16 + cc] = h2;
    }
    gbar(bar, &nbar);

    // ---- D2: pq = h2 @ W_query ----
    #pragma unroll
    for (int i = 0; i < 4; ++i) {
      int idx4 = tid + i * 512;
      int rb = idx4 >> 7, k4 = idx4 & 127;
      *(float4*)&ah[rb * AHP + 512 + k4 * 4] = *(const float4*)&h_buf[rb * 512 + k4 * 4];
    }
    __syncthreads();
    if (tid < 256) {
      int b2 = tid & 15, cc = tid >> 4;
      int qcol = wg * 16 + cc;
      const float4* wq = (const float4*)(WqT + (size_t)qcol * 512);
      const float4* hv2 = (const float4*)&ah[b2 * AHP + 512];
      float acc = 0.f;
      #pragma unroll 8
      for (int k4 = 0; k4 < 128; ++k4) {
        float4 h4 = hv2[k4], w4 = wq[k4];
        acc += h4.x * w4.x + h4.y * w4.y + h4.z * w4.z + h4.w * w4.w;
      }
      pq_buf[b2 * 512 + qcol] = acc;
    }
    gbar(bar, &nbar);

    // ---- D3: scores, masked softmax, ctx (WG b < 16 handles batch row b) ----
    if (wg < 16) {
      int bb = wg;
      pq_l[tid] = pq_buf[bb * 512 + tid];
      __syncthreads();
      int tt = tid >> 3, kk = tid & 7;
      const float* krow = keys + (size_t)(bb * TE_ + tt) * 512 + kk * 64;
      const float* pqp = pq_l + kk * 64;
      const float* vp = v_l + kk * 64;
      float s = 0.f;
      #pragma unroll 4
      for (int k = 0; k < 64; ++k) s += vp[k] * tanh_(krow[k] + pqp[k]);
      sc_part[tt][kk] = s;
      __syncthreads();
      if (tid < 64) {
        float sum = 0.f;
        #pragma unroll
        for (int q = 0; q < 8; ++q) sum += sc_part[tid][q];
        float sc = (tid < el[bb]) ? sum : -1e9f;
        float m = sc;
        for (int o = 32; o > 0; o >>= 1) m = fmaxf(m, __shfl_xor(m, o));
        float p = __expf(sc - m);
        float l = p;
        for (int o = 32; o > 0; o >>= 1) l += __shfl_xor(l, o);
        align_l[tid] = p / l;
      }
      __syncthreads();
      float acc = 0.f;
      const float* eb = enc_out + (size_t)bb * TE_ * 512 + tid;
      #pragma unroll 8
      for (int t2 = 0; t2 < TE_; ++t2) acc += align_l[t2] * eb[(size_t)t2 * 512];
      ctx_buf[bb * 512 + tid] = acc;
    }
    gbar(bar, &nbar);

    // ---- D4: attn2 = [h2|ctx] @ W_attn ----
    #pragma unroll
    for (int i = 0; i < 8; ++i) {
      int idx4 = tid + i * 512;
      int rb = idx4 >> 8, k4 = idx4 & 255;
      float4 v;
      if (k4 < 128) v = *(const float4*)&h_buf[rb * 512 + k4 * 4];
      else          v = *(const float4*)&ctx_buf[rb * 512 + (k4 - 128) * 4];
      *(float4*)&ah[rb * AHP + k4 * 4] = v;
    }
    __syncthreads();
    if (tid < 256) {
      int b2 = tid & 15, cc = tid >> 4;
      int acol = wg * 16 + cc;
      const float4* wa = (const float4*)(WaT + (size_t)acol * 1024);
      const float4* xv = (const float4*)&ah[b2 * AHP];
      float acc = 0.f;
      #pragma unroll 8
      for (int k4 = 0; k4 < 256; ++k4) {
        float4 h4 = xv[k4], w4 = wa[k4];
        acc += h4.x * w4.x + h4.y * w4.y + h4.z * w4.z + h4.w * w4.w;
      }
      attn_buf[b2 * 512 + acol] = acc;
      attn_bf[(size_t)(b2 * TD_ + t) * 512 + acol] = f2bf(acc);
    }
    gbar(bar, &nbar);
  }
}

// ---------------- projection: logits[512][90000] = attn_bf @ bf16(W_proj), masked ----------------
__global__ __launch_bounds__(512) void k_proj(
    const float* __restrict__ Wp, const unsigned short* __restrict__ Abf,
    const int* __restrict__ dec_len_g, float* __restrict__ out)
{
  __shared__ unsigned short Al[512 * 40];
  __shared__ unsigned short Bl[128 * 40];
  __shared__ int dl[16];
  const int tid = threadIdx.x;
  const int n0 = blockIdx.x * 128;
  const int wave = tid >> 6, lane = tid & 63;
  if (tid < 16) dl[tid] = dec_len_g[tid];
  f32x4 acc[4][8] = {};
  for (int kc = 0; kc < 16; ++kc) {
    const int k0 = kc * 32;
    {
      const unsigned short* src = Abf + (size_t)tid * 512 + k0;
      unsigned short* dst = Al + tid * 40;
      *(uint4*)(dst)      = *(const uint4*)(src);
      *(uint4*)(dst + 8)  = *(const uint4*)(src + 8);
      *(uint4*)(dst + 16) = *(const uint4*)(src + 16);
      *(uint4*)(dst + 24) = *(const uint4*)(src + 24);
    }
    {
      int kk = tid >> 4;
      int nn = (tid & 15) * 8;
      const float* src = Wp + (size_t)(k0 + kk) * V_ + n0 + nn;
      #pragma unroll
      for (int j = 0; j < 8; ++j) {
        float v = (n0 + nn + j < V_) ? src[j] : 0.f;
        Bl[(nn + j) * 40 + kk] = f2bf(v);
      }
    }
    __syncthreads();
    short8 bfr[8];
    #pragma unroll
    for (int nt = 0; nt < 8; ++nt)
      bfr[nt] = *(const short8*)&Bl[(nt * 16 + (lane & 15)) * 40 + (lane >> 4) * 8];
    #pragma unroll
    for (int mt = 0; mt < 4; ++mt) {
      short8 af = *(const short8*)&Al[(wave * 64 + mt * 16 + (lane & 15)) * 40 + (lane >> 4) * 8];
      #pragma unroll
      for (int nt = 0; nt < 8; ++nt)
        acc[mt][nt] = __builtin_amdgcn_mfma_f32_16x16x32_bf16(af, bfr[nt], acc[mt][nt], 0, 0, 0);
    }
    __syncthreads();
  }
  #pragma unroll
  for (int mt = 0; mt < 4; ++mt) {
    #pragma unroll
    for (int e = 0; e < 4; ++e) {
      int r = wave * 64 + mt * 16 + ((lane >> 4) << 2) + e;
      bool valid = (r & 31) < dl[r >> 5];
      #pragma unroll
      for (int nt = 0; nt < 8; ++nt) {
        int gcol = n0 + nt * 16 + (lane & 15);
        if (gcol < V_)
          out[(size_t)r * V_ + gcol] = valid ? acc[mt][nt][e] : 0.f;
      }
    }
  }
}

extern "C" void kernel_launch(void* const* d_in, const int* in_sizes, int n_in,
                              void* d_out, int out_size, void* d_ws, size_t ws_size,
                              hipStream_t stream) {
  const int* enc_in   = (const int*)d_in[0];
  const int* dec_in   = (const int*)d_in[1];
  const int* enc_len  = (const int*)d_in[2];
  const int* dec_len  = (const int*)d_in[3];
  const float* emb    = (const float*)d_in[4];
  const float* W_enc  = (const float*)d_in[5];
  const float* b_enc  = (const float*)d_in[6];
  const float* W_dec  = (const float*)d_in[7];
  const float* b_dec  = (const float*)d_in[8];
  const float* W_mem  = (const float*)d_in[9];
  const float* W_query= (const float*)d_in[10];
  const float* v_att  = (const float*)d_in[11];
  const float* W_attn = (const float*)d_in[12];
  const float* W_proj = (const float*)d_in[13];
  float* out = (float*)d_out;
  char* ws = (char*)d_ws;

  unsigned* bar        = (unsigned*)(ws + 0);
  float* h_buf         = (float*)(ws + 256);
  float* attn_buf      = (float*)(ws + 33024);
  float* ctx_buf       = (float*)(ws + 65792);
  float* pq_buf        = (float*)(ws + 98560);
  unsigned short* attn_bf = (unsigned short*)(ws + 131328);
  float* enc_out       = (float*)(ws + 655616);
  float* keys          = (float*)(ws + 2752768);
  float* Xge           = (float*)(ws + 4849920);
  float* Xgd           = (float*)(ws + 13238528);
  float* UeT           = (float*)(ws + 17432832);
  float* UdT           = (float*)(ws + 21627136);
  float* WqT           = (float*)(ws + 30015744);
  float* WmT           = (float*)(ws + 31064320);
  float* WaT           = (float*)(ws + 32112896);

  // zero: barrier counter + h_buf + attn_buf (initial states)
  hipMemsetAsync(ws, 0, 65792, stream);

  k_tr<<<4096, 256, 0, stream>>>(W_enc, W_dec, W_query, W_mem, W_attn,
                                 UeT, UdT, WqT, WmT, WaT);
  k_xg<<<dim3(32, 16), 256, 0, stream>>>(enc_in, emb, W_enc, b_enc, Xge);
  k_xg<<<dim3(32, 8),  256, 0, stream>>>(dec_in, emb, W_dec, b_dec, Xgd);
  k_coop<<<NWG, 512, 0, stream>>>(enc_len, v_att, Xge, Xgd, UeT, UdT, WqT, WmT, WaT,
                                  h_buf, attn_buf, ctx_buf, pq_buf, enc_out, keys,
                                  attn_bf, bar);
  k_proj<<<704, 512, 0, stream>>>(W_proj, attn_bf, dec_len, out);
}

// Round 2
// 4091.052 us; speedup vs baseline: 1.3864x; 1.3864x over previous
//
#include <hip/hip_runtime.h>

#define E_  256
#define H_  512
#define B_  16
#define TE_ 64
#define TD_ 32
#define V_  90000
#define G4_ 2048

typedef __attribute__((ext_vector_type(8))) short short8;
typedef __attribute__((ext_vector_type(4))) float f32x4;
typedef _Float16 half2_ __attribute__((ext_vector_type(2)));

__device__ __forceinline__ float sigm(float x) { return 1.f / (1.f + __expf(-x)); }
__device__ __forceinline__ float tanh_(float x) {
  float e = __expf(-2.f * fabsf(x));
  float r = (1.f - e) / (1.f + e);
  return x >= 0.f ? r : -r;
}
__device__ __forceinline__ unsigned short f2bf(float v) {
  union { float f; unsigned u; } c; c.f = v;
  unsigned r = c.u + 0x7FFFu + ((c.u >> 16) & 1u);
  return (unsigned short)(r >> 16);
}
__device__ __forceinline__ unsigned pack2(float a, float b) {
  union { unsigned u; _Float16 h[2]; } p;
  p.h[0] = (_Float16)a; p.h[1] = (_Float16)b;   // RNE, low half = even index
  return p.u;
}
__device__ __forceinline__ float dot2u(unsigned w, unsigned h, float acc) {
#if __has_builtin(__builtin_amdgcn_fdot2)
  union { unsigned u; half2_ v; } a, b; a.u = w; b.u = h;
  return __builtin_amdgcn_fdot2(a.v, b.v, acc, false);
#else
  union { unsigned u; _Float16 h[2]; } a, b; a.u = w; b.u = h;
  return acc + (float)a.h[0] * (float)b.h[0] + (float)a.h[1] * (float)b.h[1];
#endif
}
__device__ __forceinline__ float dot8(uint4 w, uint4 h, float acc) {
  acc = dot2u(w.x, h.x, acc);
  acc = dot2u(w.y, h.y, acc);
  acc = dot2u(w.z, h.z, acc);
  acc = dot2u(w.w, h.w, acc);
  return acc;
}

// ---------------- f16 pack of recurrent weight blocks, layout [kc][col][8] halves ----------------
// Ue: W_enc rows 256..767   -> [64][2048][8]
// Ud: W_dec rows 256..1279  -> [128][2048][8]   (k = [attn(512)|h(512)])
// Wq: W_query               -> [64][512][8]
// Wa: W_attn                -> [128][512][8]    (k = [h|ctx])
// Wm: W_mem                 -> [64][512][8]
__global__ __launch_bounds__(256) void k_cv(
    const float* __restrict__ W_enc, const float* __restrict__ W_dec,
    const float* __restrict__ W_query, const float* __restrict__ W_attn,
    const float* __restrict__ W_mem,
    uint4* __restrict__ Ue, uint4* __restrict__ Ud, uint4* __restrict__ Wq,
    uint4* __restrict__ Wa, uint4* __restrict__ Wm)
{
  int u = blockIdx.x * 256 + threadIdx.x;
  const float* src; uint4* dst; int C, r0, lu;
  if (u < 131072)      { src = W_enc;   dst = Ue; C = 2048; r0 = 256; lu = u; }
  else if (u < 393216) { src = W_dec;   dst = Ud; C = 2048; r0 = 256; lu = u - 131072; }
  else if (u < 425984) { src = W_query; dst = Wq; C = 512;  r0 = 0;   lu = u - 393216; }
  else if (u < 491520) { src = W_attn;  dst = Wa; C = 512;  r0 = 0;   lu = u - 425984; }
  else                 { src = W_mem;   dst = Wm; C = 512;  r0 = 0;   lu = u - 491520; }
  int kc = lu / C, col = lu - kc * C;
  union { uint4 v; _Float16 h[8]; } p;
  #pragma unroll
  for (int e = 0; e < 8; ++e)
    p.h[e] = (_Float16)src[(size_t)(r0 + kc * 8 + e) * C + col];
  dst[(size_t)kc * C + col] = p.v;
}

// ---------------- x-part of LSTM gates: Xg[tok][2048] = emb[tok]@W[0:256,:] + b ----------------
__global__ __launch_bounds__(256) void k_xg(
    const int* __restrict__ toks, const float* __restrict__ emb,
    const float* __restrict__ W, const float* __restrict__ bias,
    float* __restrict__ Xg)
{
  const int tid = threadIdx.x;
  const int cc = tid & 63;
  const int tg = tid >> 6;
  const int col = blockIdx.x * 64 + cc;
  const int t0 = blockIdx.y * 64 + tg * 16;
  const float* ep[16];
  #pragma unroll
  for (int i = 0; i < 16; ++i) ep[i] = emb + (size_t)toks[t0 + i] * E_;
  float acc[16];
  float bv = bias[col];
  #pragma unroll
  for (int i = 0; i < 16; ++i) acc[i] = bv;
  for (int k4 = 0; k4 < 64; ++k4) {
    float w0 = W[(size_t)(k4 * 4 + 0) * G4_ + col];
    float w1 = W[(size_t)(k4 * 4 + 1) * G4_ + col];
    float w2 = W[(size_t)(k4 * 4 + 2) * G4_ + col];
    float w3 = W[(size_t)(k4 * 4 + 3) * G4_ + col];
    #pragma unroll
    for (int i = 0; i < 16; ++i) {
      float4 e4 = *(const float4*)(ep[i] + k4 * 4);
      acc[i] += e4.x * w0 + e4.y * w1 + e4.z * w2 + e4.w * w3;
    }
  }
  #pragma unroll
  for (int i = 0; i < 16; ++i)
    Xg[(size_t)(t0 + i) * G4_ + col] = acc[i];
}

// ---------------- encoder: one WG per batch element, zero grid sync ----------------
__global__ __launch_bounds__(512) void k_enc(
    const int* __restrict__ enc_len, const float* __restrict__ Xge,
    const uint4* __restrict__ Ue,
    float* __restrict__ enc_out, unsigned* __restrict__ enc_f16,
    unsigned* __restrict__ hp_st, float* __restrict__ c_st)
{
  __shared__ __align__(16) unsigned hp[256];   // h packed f16 pairs
  const int b = blockIdx.x, tid = threadIdx.x;
  const int el = enc_len[b];
  if (tid < 256) hp[tid] = 0;
  float c = 0.f, h = 0.f;
  __syncthreads();
  for (int t = 0; t < TE_; ++t) {
    const float* xg = Xge + (size_t)(b * TE_ + t) * G4_;
    float a0 = xg[tid], a1 = xg[512 + tid], a2 = xg[1024 + tid], a3 = xg[1536 + tid];
    const uint4* hv = (const uint4*)hp;
    const uint4* u = Ue + tid;
    #pragma unroll 2
    for (int kc = 0; kc < 64; ++kc) {
      uint4 h8 = hv[kc];
      uint4 w0 = u[(size_t)kc * 2048];
      uint4 w1 = u[(size_t)kc * 2048 + 512];
      uint4 w2 = u[(size_t)kc * 2048 + 1024];
      uint4 w3 = u[(size_t)kc * 2048 + 1536];
      a0 = dot8(w0, h8, a0);
      a1 = dot8(w1, h8, a1);
      a2 = dot8(w2, h8, a2);
      a3 = dot8(w3, h8, a3);
    }
    __syncthreads();   // all lanes done reading hp
    float c2 = c * sigm(a2 + 1.f) + sigm(a0) * tanh_(a1);
    float h2 = tanh_(c2) * sigm(a3);
    bool valid = t < el;
    c = valid ? c2 : c;
    h = valid ? h2 : h;
    float eo = valid ? h2 : 0.f;
    enc_out[(size_t)(b * TE_ + t) * 512 + tid] = eo;
    float hn = __shfl_xor(h, 1);
    float eon = __shfl_xor(eo, 1);
    if (!(tid & 1)) {
      hp[tid >> 1] = pack2(h, hn);
      enc_f16[(size_t)(b * TE_ + t) * 256 + (tid >> 1)] = pack2(eo, eon);
    }
    __syncthreads();
  }
  float hn = __shfl_xor(h, 1);
  if (!(tid & 1)) hp_st[b * 256 + (tid >> 1)] = pack2(h, hn);
  c_st[b * 512 + tid] = c;
}

// ---------------- keys = enc_out @ W_mem (full grid, f16 dot2) ----------------
__global__ __launch_bounds__(512) void k_keys(
    const unsigned* __restrict__ enc_f16, const uint4* __restrict__ Wm,
    float* __restrict__ keys)
{
  __shared__ __align__(16) unsigned At[1024];   // 4 rows x 256 uints
  const int bq = blockIdx.x;
  const int b = bq >> 4, tq = bq & 15;
  const int tid = threadIdx.x;
  const size_t base = (size_t)(b * TE_ + tq * 4) * 256;
  At[tid] = enc_f16[base + tid];
  At[512 + tid] = enc_f16[base + 512 + tid];
  __syncthreads();
  float acc0 = 0.f, acc1 = 0.f, acc2 = 0.f, acc3 = 0.f;
  const uint4* av = (const uint4*)At;
  const uint4* w = Wm + tid;
  #pragma unroll 2
  for (int kc = 0; kc < 64; ++kc) {
    uint4 ww = w[(size_t)kc * 512];
    uint4 h0 = av[kc], h1 = av[64 + kc], h2 = av[128 + kc], h3 = av[192 + kc];
    acc0 = dot8(ww, h0, acc0);
    acc1 = dot8(ww, h1, acc1);
    acc2 = dot8(ww, h2, acc2);
    acc3 = dot8(ww, h3, acc3);
  }
  const size_t kb = (size_t)(b * TE_ + tq * 4) * 512 + tid;
  keys[kb]            = acc0;
  keys[kb + 512]      = acc1;
  keys[kb + 1024]     = acc2;
  keys[kb + 1536]     = acc3;
}

// ---------------- decoder: one WG per batch element, block-local sync only ----------------
__global__ __launch_bounds__(512) void k_dec(
    const int* __restrict__ enc_len, const float* __restrict__ v_att,
    const float* __restrict__ Xgd,
    const uint4* __restrict__ Ud, const uint4* __restrict__ Wq,
    const uint4* __restrict__ Wa,
    const float* __restrict__ enc_out, const float* __restrict__ keys,
    const unsigned* __restrict__ hp_st, const float* __restrict__ c_st,
    unsigned short* __restrict__ attn_bf)
{
  __shared__ __align__(16) unsigned inp1[512];  // [attn(256)|h(256)] packed pairs
  __shared__ __align__(16) unsigned inp2[512];  // [h(256)|ctx(256)] packed pairs
  __shared__ __align__(16) float pq[512];
  __shared__ __align__(16) float vl[512];
  __shared__ float scp[64][9];
  __shared__ float align_l[64];
  const int b = blockIdx.x, tid = threadIdx.x;
  const int el = enc_len[b];
  vl[tid] = v_att[tid];
  if (tid < 256) {
    unsigned hh = hp_st[b * 256 + tid];
    inp1[tid] = 0;          // attn0 = 0
    inp1[256 + tid] = hh;
    inp2[tid] = hh;
  }
  float c = c_st[b * 512 + tid];
  __syncthreads();
  for (int t = 0; t < TD_; ++t) {
    // ---- D1: LSTM gates = Xgd + [attn|h] @ Ud ----
    const float* xg = Xgd + (size_t)(b * TD_ + t) * G4_;
    float a0 = xg[tid], a1 = xg[512 + tid], a2 = xg[1024 + tid], a3 = xg[1536 + tid];
    {
      const uint4* iv = (const uint4*)inp1;
      const uint4* u = Ud + tid;
      #pragma unroll 2
      for (int kc = 0; kc < 128; ++kc) {
        uint4 h8 = iv[kc];
        uint4 w0 = u[(size_t)kc * 2048];
        uint4 w1 = u[(size_t)kc * 2048 + 512];
        uint4 w2 = u[(size_t)kc * 2048 + 1024];
        uint4 w3 = u[(size_t)kc * 2048 + 1536];
        a0 = dot8(w0, h8, a0);
        a1 = dot8(w1, h8, a1);
        a2 = dot8(w2, h8, a2);
        a3 = dot8(w3, h8, a3);
      }
    }
    __syncthreads();   // done reading inp1
    float c2 = c * sigm(a2 + 1.f) + sigm(a0) * tanh_(a1);
    float h2 = tanh_(c2) * sigm(a3);
    c = c2;
    {
      float hn = __shfl_xor(h2, 1);
      if (!(tid & 1)) {
        unsigned pk = pack2(h2, hn);
        inp1[256 + (tid >> 1)] = pk;
        inp2[tid >> 1] = pk;
      }
    }
    __syncthreads();
    // ---- D2: pq = h2 @ W_query ----
    {
      float acc = 0.f;
      const uint4* hv = ((const uint4*)inp1) + 64;
      const uint4* w = Wq + tid;
      #pragma unroll 2
      for (int kc = 0; kc < 64; ++kc)
        acc = dot8(w[(size_t)kc * 512], hv[kc], acc);
      pq[tid] = acc;
    }
    __syncthreads();
    // ---- D3: scores ----
    {
      int tt = tid >> 3, kg = tid & 7;
      const float4* kr = (const float4*)(keys + (size_t)(b * TE_ + tt) * 512 + kg * 64);
      const float4* pp = (const float4*)(pq + kg * 64);
      const float4* vp = (const float4*)(vl + kg * 64);
      float s = 0.f;
      #pragma unroll 4
      for (int i = 0; i < 16; ++i) {
        float4 k4 = kr[i], p4 = pp[i], v4 = vp[i];
        s += v4.x * tanh_(k4.x + p4.x) + v4.y * tanh_(k4.y + p4.y)
           + v4.z * tanh_(k4.z + p4.z) + v4.w * tanh_(k4.w + p4.w);
      }
      scp[tt][kg] = s;
    }
    __syncthreads();
    if (tid < 64) {
      float sum = 0.f;
      #pragma unroll
      for (int q = 0; q < 8; ++q) sum += scp[tid][q];
      float sc = (tid < el) ? sum : -1e9f;
      float m = sc;
      for (int o = 32; o > 0; o >>= 1) m = fmaxf(m, __shfl_xor(m, o));
      float p = __expf(sc - m);
      float l = p;
      for (int o = 32; o > 0; o >>= 1) l += __shfl_xor(l, o);
      align_l[tid] = p / l;
    }
    __syncthreads();
    // ---- D4: ctx ----
    {
      float acc = 0.f;
      const float* eb = enc_out + (size_t)b * TE_ * 512 + tid;
      #pragma unroll 8
      for (int t2 = 0; t2 < TE_; ++t2) acc += align_l[t2] * eb[(size_t)t2 * 512];
      float an = __shfl_xor(acc, 1);
      if (!(tid & 1)) inp2[256 + (tid >> 1)] = pack2(acc, an);
    }
    __syncthreads();
    // ---- D5: attn2 = [h2|ctx] @ W_attn ----
    {
      float acc = 0.f;
      const uint4* iv2 = (const uint4*)inp2;
      const uint4* w = Wa + tid;
      #pragma unroll 2
      for (int kc = 0; kc < 128; ++kc)
        acc = dot8(w[(size_t)kc * 512], iv2[kc], acc);
      attn_bf[(size_t)(b * TD_ + t) * 512 + tid] = f2bf(acc);
      float an = __shfl_xor(acc, 1);
      if (!(tid & 1)) inp1[tid >> 1] = pack2(acc, an);
    }
    __syncthreads();
  }
}

// ---------------- projection: logits[512][90000] = attn_bf @ bf16(W_proj), masked ----------------
__global__ __launch_bounds__(512) void k_proj(
    const float* __restrict__ Wp, const unsigned short* __restrict__ Abf,
    const int* __restrict__ dec_len_g, float* __restrict__ out)
{
  __shared__ unsigned short Al[512 * 40];
  __shared__ unsigned short Bl[128 * 40];
  __shared__ int dl[16];
  const int tid = threadIdx.x;
  const int n0 = blockIdx.x * 128;
  const int wave = tid >> 6, lane = tid & 63;
  if (tid < 16) dl[tid] = dec_len_g[tid];
  f32x4 acc[4][8] = {};
  for (int kc = 0; kc < 16; ++kc) {
    const int k0 = kc * 32;
    {
      const unsigned short* src = Abf + (size_t)tid * 512 + k0;
      unsigned short* dst = Al + tid * 40;
      *(uint4*)(dst)      = *(const uint4*)(src);
      *(uint4*)(dst + 8)  = *(const uint4*)(src + 8);
      *(uint4*)(dst + 16) = *(const uint4*)(src + 16);
      *(uint4*)(dst + 24) = *(const uint4*)(src + 24);
    }
    {
      int kk = tid >> 4;
      int nn = (tid & 15) * 8;
      const float* src = Wp + (size_t)(k0 + kk) * V_ + n0 + nn;
      #pragma unroll
      for (int j = 0; j < 8; ++j) {
        float v = (n0 + nn + j < V_) ? src[j] : 0.f;
        Bl[(nn + j) * 40 + kk] = f2bf(v);
      }
    }
    __syncthreads();
    short8 bfr[8];
    #pragma unroll
    for (int nt = 0; nt < 8; ++nt)
      bfr[nt] = *(const short8*)&Bl[(nt * 16 + (lane & 15)) * 40 + (lane >> 4) * 8];
    #pragma unroll
    for (int mt = 0; mt < 4; ++mt) {
      short8 af = *(const short8*)&Al[(wave * 64 + mt * 16 + (lane & 15)) * 40 + (lane >> 4) * 8];
      #pragma unroll
      for (int nt = 0; nt < 8; ++nt)
        acc[mt][nt] = __builtin_amdgcn_mfma_f32_16x16x32_bf16(af, bfr[nt], acc[mt][nt], 0, 0, 0);
    }
    __syncthreads();
  }
  #pragma unroll
  for (int mt = 0; mt < 4; ++mt) {
    #pragma unroll
    for (int e = 0; e < 4; ++e) {
      int r = wave * 64 + mt * 16 + ((lane >> 4) << 2) + e;
      bool valid = (r & 31) < dl[r >> 5];
      #pragma unroll
      for (int nt = 0; nt < 8; ++nt) {
        int gcol = n0 + nt * 16 + (lane & 15);
        if (gcol < V_)
          out[(size_t)r * V_ + gcol] = valid ? acc[mt][nt][e] : 0.f;
      }
    }
  }
}

extern "C" void kernel_launch(void* const* d_in, const int* in_sizes, int n_in,
                              void* d_out, int out_size, void* d_ws, size_t ws_size,
                              hipStream_t stream) {
  const int* enc_in   = (const int*)d_in[0];
  const int* dec_in   = (const int*)d_in[1];
  const int* enc_len  = (const int*)d_in[2];
  const int* dec_len  = (const int*)d_in[3];
  const float* emb    = (const float*)d_in[4];
  const float* W_enc  = (const float*)d_in[5];
  const float* b_enc  = (const float*)d_in[6];
  const float* W_dec  = (const float*)d_in[7];
  const float* b_dec  = (const float*)d_in[8];
  const float* W_mem  = (const float*)d_in[9];
  const float* W_query= (const float*)d_in[10];
  const float* v_att  = (const float*)d_in[11];
  const float* W_attn = (const float*)d_in[12];
  const float* W_proj = (const float*)d_in[13];
  float* out = (float*)d_out;
  char* ws = (char*)d_ws;

  float* Xge          = (float*)(ws + 0);          //  8 MB
  float* Xgd          = (float*)(ws + 8388608);    //  4 MB
  uint4* Ue           = (uint4*)(ws + 12582912);   //  2 MB
  uint4* Ud           = (uint4*)(ws + 14680064);   //  4 MB
  uint4* Wq           = (uint4*)(ws + 18874368);   // 0.5 MB
  uint4* Wa           = (uint4*)(ws + 19398656);   //  1 MB
  uint4* Wm           = (uint4*)(ws + 20447232);   // 0.5 MB
  float* enc_out      = (float*)(ws + 20971520);   //  2 MB
  unsigned* enc_f16   = (unsigned*)(ws + 23068672);//  1 MB
  float* keys         = (float*)(ws + 24117248);   //  2 MB
  unsigned short* attn_bf = (unsigned short*)(ws + 26214400); // 0.5 MB
  unsigned* hp_st     = (unsigned*)(ws + 26738688);
  float* c_st         = (float*)(ws + 26755072);

  k_cv<<<2048, 256, 0, stream>>>(W_enc, W_dec, W_query, W_attn, W_mem,
                                 Ue, Ud, Wq, Wa, Wm);
  k_xg<<<dim3(32, 16), 256, 0, stream>>>(enc_in, emb, W_enc, b_enc, Xge);
  k_xg<<<dim3(32, 8),  256, 0, stream>>>(dec_in, emb, W_dec, b_dec, Xgd);
  k_enc<<<B_, 512, 0, stream>>>(enc_len, Xge, Ue, enc_out, enc_f16, hp_st, c_st);
  k_keys<<<256, 512, 0, stream>>>(enc_f16, Wm, keys);
  k_dec<<<B_, 512, 0, stream>>>(enc_len, v_att, Xgd, Ud, Wq, Wa,
                                enc_out, keys, hp_st, c_st, attn_bf);
  k_proj<<<704, 512, 0, stream>>>(W_proj, attn_bf, dec_len, out);
}